// Round 2
// baseline (812.912 us; speedup 1.0000x reference)
//
#include <hip/hip_runtime.h>

// Problem constants (fixed shapes from the reference).
#define T_TYPES 27
#define N_NODES 16384
#define B_BATCH 256
#define IN_DIM 300
#define HID 128
#define OUTD 64

#define RPB 32          // batch rows per MLP block
#define VEC 75          // 300 floats = 75 float4 per row

// ---------------------------------------------------------------------------
// Kernel 0: segment boundary precompute.
// seg is sorted per type; bounds[t][v] = lower_bound(seg[t], v) for v in
// [0, B], via change detection (one pass, no per-block binary search later).
// grid 27, block 256.
// ---------------------------------------------------------------------------
__global__ __launch_bounds__(256) void bounds_kernel(
    const int* __restrict__ seg,     // [T, N] sorted in [0, B)
    int*       __restrict__ bounds)  // [T, B+1]
{
    const int t = blockIdx.x;
    const int* __restrict__ s = seg + (size_t)t * N_NODES;
    int* __restrict__ bt = bounds + t * (B_BATCH + 1);
    for (int i = threadIdx.x; i <= N_NODES; i += 256) {
        const int cur  = (i < N_NODES) ? s[i] : B_BATCH;
        const int prev = (i > 0) ? s[i - 1] : -1;
        for (int v = prev + 1; v <= cur; ++v) bt[v] = i;
    }
}

// ---------------------------------------------------------------------------
// Kernel 1: ragged segment mean pooling.
// One block per (t, b): contiguous node range [bounds[b], bounds[b+1]).
// Block (80, 2): x = float4 column (75 active), y = node phase (2-way).
// 8-deep unroll -> 8 outstanding float4 loads per lane; 160-thread blocks
// give 12 resident blocks/CU -> ~240 outstanding 1KB loads per CU.
// ---------------------------------------------------------------------------
__global__ __launch_bounds__(160) void pool_kernel(
    const float* __restrict__ feat,   // [T, N, 300]
    const int*   __restrict__ bounds, // [T, B+1]
    float*       __restrict__ pooled) // [T, B, 300]
{
    const int b = blockIdx.x;
    const int t = blockIdx.y;
    const int x = threadIdx.x;
    const int y = threadIdx.y;

    const int start = bounds[t * (B_BATCH + 1) + b];
    const int end   = bounds[t * (B_BATCH + 1) + b + 1];

    __shared__ float4 sAcc[80];

    float4 acc = make_float4(0.f, 0.f, 0.f, 0.f);
    if (x < VEC) {
        const float4* __restrict__ fv = (const float4*)feat;
        const size_t rowBase = (size_t)t * N_NODES;
        int n = start + y;
        // 8 outstanding float4 loads per lane per iteration
        for (; n + 14 < end; n += 16) {
            float4 v0 = fv[(rowBase + n     ) * VEC + x];
            float4 v1 = fv[(rowBase + n + 2 ) * VEC + x];
            float4 v2 = fv[(rowBase + n + 4 ) * VEC + x];
            float4 v3 = fv[(rowBase + n + 6 ) * VEC + x];
            float4 v4 = fv[(rowBase + n + 8 ) * VEC + x];
            float4 v5 = fv[(rowBase + n + 10) * VEC + x];
            float4 v6 = fv[(rowBase + n + 12) * VEC + x];
            float4 v7 = fv[(rowBase + n + 14) * VEC + x];
            acc.x += ((v0.x + v1.x) + (v2.x + v3.x)) + ((v4.x + v5.x) + (v6.x + v7.x));
            acc.y += ((v0.y + v1.y) + (v2.y + v3.y)) + ((v4.y + v5.y) + (v6.y + v7.y));
            acc.z += ((v0.z + v1.z) + (v2.z + v3.z)) + ((v4.z + v5.z) + (v6.z + v7.z));
            acc.w += ((v0.w + v1.w) + (v2.w + v3.w)) + ((v4.w + v5.w) + (v6.w + v7.w));
        }
        for (; n < end; n += 2) {
            float4 v = fv[(rowBase + n) * VEC + x];
            acc.x += v.x; acc.y += v.y; acc.z += v.z; acc.w += v.w;
        }
    }
    if (y == 1) sAcc[x] = acc;
    __syncthreads();

    if (y == 0 && x < VEC) {
        const float4 a1 = sAcc[x];
        const int cnt = end - start;
        const float scale = (cnt > 0) ? (1.0f / (float)cnt) : 0.0f;
        float4 r;
        r.x = (acc.x + a1.x) * scale;
        r.y = (acc.y + a1.y) * scale;
        r.z = (acc.z + a1.z) * scale;
        r.w = (acc.w + a1.w) * scale;
        ((float4*)pooled)[((size_t)t * B_BATCH + b) * VEC + x] = r;
    }
}

// ---------------------------------------------------------------------------
// Kernel 2: per-type 2-layer MLP on pooled rows (unchanged, known-correct).
// grid (B/RPB, T), block 256. 32 pooled rows staged in LDS (stride 301,
// odd -> conflict-free). W1/W2 reads are lane-broadcast across r-lanes.
// ---------------------------------------------------------------------------
__global__ __launch_bounds__(256) void mlp_kernel(
    const float* __restrict__ pooled, // [T, B, 300]
    const float* __restrict__ W1,     // [T, 300, 128]
    const float* __restrict__ b1,     // [T, 128]
    const float* __restrict__ W2,     // [T, 128, 64]
    const float* __restrict__ b2,     // [T, 64]
    float*       __restrict__ out)    // [B, T, 64]
{
    const int t  = blockIdx.y;
    const int b0 = blockIdx.x * RPB;
    const int tid = threadIdx.x;

    __shared__ float sP[RPB][IN_DIM + 1]; // stride 301 (odd)
    __shared__ float sH[RPB][HID + 1];    // stride 129 (odd)

    {
        const float* __restrict__ psrc =
            pooled + ((size_t)t * B_BATCH + b0) * IN_DIM;
        for (int idx = tid; idx < RPB * IN_DIM; idx += 256) {
            int r = idx / IN_DIM;
            int i = idx - r * IN_DIM;
            sP[r][i] = psrc[idx];
        }
    }
    __syncthreads();

    // ---- layer 1: h = relu(p @ W1 + b1) ----
    {
        const int r  = tid & 31;
        const int hq = tid >> 5;          // 8 groups x 16 h
        float acc[16];
        {
            const float* __restrict__ bb = b1 + t * HID + hq * 16;
            #pragma unroll
            for (int j = 0; j < 16; ++j) acc[j] = bb[j];
        }
        const float* __restrict__ w1p =
            W1 + (size_t)t * IN_DIM * HID + hq * 16;
        #pragma unroll 2
        for (int i = 0; i < IN_DIM; ++i) {
            const float p = sP[r][i];
            const float4* __restrict__ w = (const float4*)(w1p + (size_t)i * HID);
            float4 wv[4];
            wv[0] = w[0]; wv[1] = w[1]; wv[2] = w[2]; wv[3] = w[3];
            #pragma unroll
            for (int q = 0; q < 4; ++q) {
                acc[q * 4 + 0] += p * wv[q].x;
                acc[q * 4 + 1] += p * wv[q].y;
                acc[q * 4 + 2] += p * wv[q].z;
                acc[q * 4 + 3] += p * wv[q].w;
            }
        }
        #pragma unroll
        for (int j = 0; j < 16; ++j)
            sH[r][hq * 16 + j] = fmaxf(acc[j], 0.0f);
    }
    __syncthreads();

    // ---- layer 2: out = h @ W2 + b2 ----
    {
        const int r  = tid & 31;
        const int oq = tid >> 5;          // 8 groups x 8 outputs
        float acc[8];
        {
            const float* __restrict__ bb = b2 + t * OUTD + oq * 8;
            #pragma unroll
            for (int j = 0; j < 8; ++j) acc[j] = bb[j];
        }
        const float* __restrict__ w2p =
            W2 + (size_t)t * HID * OUTD + oq * 8;
        #pragma unroll 2
        for (int k = 0; k < HID; ++k) {
            const float h = sH[r][k];
            const float4* __restrict__ w = (const float4*)(w2p + (size_t)k * OUTD);
            float4 w0 = w[0], w1v = w[1];
            acc[0] += h * w0.x;  acc[1] += h * w0.y;
            acc[2] += h * w0.z;  acc[3] += h * w0.w;
            acc[4] += h * w1v.x; acc[5] += h * w1v.y;
            acc[6] += h * w1v.z; acc[7] += h * w1v.w;
        }
        float* __restrict__ op =
            out + ((size_t)(b0 + r) * T_TYPES + t) * OUTD + oq * 8;
        #pragma unroll
        for (int j = 0; j < 8; ++j) op[j] = acc[j];
    }
}

extern "C" void kernel_launch(void* const* d_in, const int* in_sizes, int n_in,
                              void* d_out, int out_size, void* d_ws, size_t ws_size,
                              hipStream_t stream) {
    const float* feat = (const float*)d_in[0];
    const int*   seg  = (const int*)  d_in[1];
    const float* W1   = (const float*)d_in[2];
    const float* b1   = (const float*)d_in[3];
    const float* W2   = (const float*)d_in[4];
    const float* b2   = (const float*)d_in[5];
    float* out = (float*)d_out;

    // ws layout: pooled [27*256*300 f32 = 8,294,400 B] then bounds [27*257 i32]
    float* pooled = (float*)d_ws;
    int*   bounds = (int*)((char*)d_ws + (size_t)T_TYPES * B_BATCH * IN_DIM * 4);

    hipLaunchKernelGGL(bounds_kernel, dim3(T_TYPES), dim3(256), 0, stream,
                       seg, bounds);

    dim3 g1(B_BATCH, T_TYPES), blk1(80, 2);
    hipLaunchKernelGGL(pool_kernel, g1, blk1, 0, stream, feat, bounds, pooled);

    dim3 g2(B_BATCH / RPB, T_TYPES), blk2(256);
    hipLaunchKernelGGL(mlp_kernel, g2, blk2, 0, stream,
                       pooled, W1, b1, W2, b2, out);
}